// Round 5
// baseline (721.550 us; speedup 1.0000x reference)
//
#include <hip/hip_runtime.h>
#include <hip/hip_fp16.h>
#include <math.h>

#define N_NODES 100000
#define N_EDGES 1600000
#define HDIM    128
#define NCLS    10
#define NGRAPH  1000
#define NREP    8          // histogram replicas (spread atomic sectors)
#define GEMM_BLOCKS ((N_NODES + 127) / 128)   // 782
#define HIST_BLOCKS ((N_EDGES + 255) / 256)   // 6250

static __device__ __forceinline__ float elu1(float x) {
  return x > 0.f ? x : (__expf(x) - 1.f);
}

// ---------- GEMM body: Ch[n,128](fp16) = A[n,128](f32) @ W[128,128](f32) ----
// 128x128 tile/block, W whole in LDS (64 KB), 8x8 reg tile/thread, pipelined
// A loads. Shared by standalone gemm_xw and the fused hist+gemm0 kernel.
__device__ __forceinline__
void gemm_body(const float* __restrict__ A, const float* __restrict__ W,
               __half* __restrict__ Ch, int nrows, float* Wl, int bid) {
  int tid = threadIdx.x;
  {
    const float4* W4 = (const float4*)W;
    float4* Wl4 = (float4*)Wl;
    for (int i = tid; i < 128 * 128 / 4; i += 256) Wl4[i] = W4[i];
  }
  __syncthreads();

  int ty = tid >> 4;
  int tx = tid & 15;
  int row0 = bid * 128 + ty * 8;

  const float4* arow[8];
#pragma unroll
  for (int r = 0; r < 8; ++r) {
    int rr = row0 + r;
    if (rr > nrows - 1) rr = nrows - 1;  // clamp tail (stores are guarded)
    arow[r] = (const float4*)&A[(size_t)rr * HDIM];
  }

  float4 acc0[8], acc1[8];
#pragma unroll
  for (int r = 0; r < 8; ++r) {
    acc0[r] = make_float4(0.f, 0.f, 0.f, 0.f);
    acc1[r] = make_float4(0.f, 0.f, 0.f, 0.f);
  }

  float4 xa[8], xb[8];
#pragma unroll
  for (int r = 0; r < 8; ++r) xa[r] = arow[r][0];

#define COMPUTE4(XV, KBASE)                                          \
  {                                                                  \
    _Pragma("unroll")                                                \
    for (int kk = 0; kk < 4; ++kk) {                                 \
      const float* wrow = &Wl[((KBASE) + kk) * 128];                 \
      float4 w0 = *(const float4*)(wrow + tx * 4);                   \
      float4 w1 = *(const float4*)(wrow + 64 + tx * 4);              \
      _Pragma("unroll")                                              \
      for (int r = 0; r < 8; ++r) {                                  \
        float xs = ((const float*)&XV[r])[kk];                       \
        acc0[r].x = fmaf(xs, w0.x, acc0[r].x);                       \
        acc0[r].y = fmaf(xs, w0.y, acc0[r].y);                       \
        acc0[r].z = fmaf(xs, w0.z, acc0[r].z);                       \
        acc0[r].w = fmaf(xs, w0.w, acc0[r].w);                       \
        acc1[r].x = fmaf(xs, w1.x, acc1[r].x);                       \
        acc1[r].y = fmaf(xs, w1.y, acc1[r].y);                       \
        acc1[r].z = fmaf(xs, w1.z, acc1[r].z);                       \
        acc1[r].w = fmaf(xs, w1.w, acc1[r].w);                       \
      }                                                              \
    }                                                                \
  }

  for (int k = 0; k < 128; k += 8) {
#pragma unroll
    for (int r = 0; r < 8; ++r) xb[r] = arow[r][(k >> 2) + 1];
    COMPUTE4(xa, k);
    if (k + 8 < 128) {
#pragma unroll
      for (int r = 0; r < 8; ++r) xa[r] = arow[r][(k >> 2) + 2];
    }
    COMPUTE4(xb, k + 4);
  }
#undef COMPUTE4

#pragma unroll
  for (int r = 0; r < 8; ++r) {
    int rr = row0 + r;
    if (rr < nrows) {
      __half2 l0 = __floats2half2_rn(acc0[r].x, acc0[r].y);
      __half2 l1 = __floats2half2_rn(acc0[r].z, acc0[r].w);
      __half2 h0 = __floats2half2_rn(acc1[r].x, acc1[r].y);
      __half2 h1 = __floats2half2_rn(acc1[r].z, acc1[r].w);
      uint2 p0, p1;
      p0.x = *(unsigned*)&l0; p0.y = *(unsigned*)&l1;
      p1.x = *(unsigned*)&h0; p1.y = *(unsigned*)&h1;
      *(uint2*)&Ch[(size_t)rr * HDIM + tx * 4] = p0;
      *(uint2*)&Ch[(size_t)rr * HDIM + 64 + tx * 4] = p1;
    }
  }
}

__global__ __launch_bounds__(256, 2)
void gemm_xw(const float* __restrict__ A, const float* __restrict__ W,
             __half* __restrict__ Ch, int nrows) {
  __shared__ float Wl[128 * 128];
  gemm_body(A, W, Ch, nrows, Wl, blockIdx.x);
}

// ---------- fused: GEMM layer0 + degree/graph histograms ----------
// GEMM0 (x@W0) is independent of CSR build; histogram blocks are
// atomic/fabric-bound with ~0.4% VALU (R4) -> near-perfect co-scheduling.
// cnt is NREP-replicated to spread atomic traffic over 8x more 32B sectors.
__global__ __launch_bounds__(256, 2)
void hist_gemm0(const float* __restrict__ A, const float* __restrict__ W,
                __half* __restrict__ Ch,
                const int* __restrict__ ei, const int* __restrict__ batch,
                int* __restrict__ cnt, int* __restrict__ gcnt) {
  __shared__ float Wl[128 * 128];
  if (blockIdx.x < GEMM_BLOCKS) {
    gemm_body(A, W, Ch, N_NODES, Wl, blockIdx.x);
  } else {
    int b = blockIdx.x - GEMM_BLOCKS;
    int e = b * 256 + threadIdx.x;
    if (e < N_EDGES) atomicAdd(&cnt[(b & (NREP - 1)) * N_NODES + ei[N_EDGES + e]], 1);
    if (e < N_NODES) atomicAdd(&gcnt[batch[e]], 1);
  }
}

// ---------- CSR build ----------

// block-local exclusive scan: 1024 elements/block (256 thr x 4); sums the
// NREP histogram replicas and emits dinv[i] = rsqrt(deg_in + 1).
__global__ void scan_local(const int* __restrict__ cnt, int* __restrict__ off,
                           int* __restrict__ bsum, float* __restrict__ dinv, int n) {
  __shared__ int s[256];
  int t = threadIdx.x;
  int base = blockIdx.x * 1024 + t * 4;
  int v0 = 0, v1 = 0, v2 = 0, v3 = 0;
#pragma unroll
  for (int r = 0; r < NREP; ++r) {
    const int* c = cnt + (size_t)r * N_NODES;
    if (base + 0 < n) v0 += c[base + 0];
    if (base + 1 < n) v1 += c[base + 1];
    if (base + 2 < n) v2 += c[base + 2];
    if (base + 3 < n) v3 += c[base + 3];
  }
  if (base + 0 < n) dinv[base + 0] = rsqrtf((float)(v0 + 1));
  if (base + 1 < n) dinv[base + 1] = rsqrtf((float)(v1 + 1));
  if (base + 2 < n) dinv[base + 2] = rsqrtf((float)(v2 + 1));
  if (base + 3 < n) dinv[base + 3] = rsqrtf((float)(v3 + 1));
  int sum = v0 + v1 + v2 + v3;
  s[t] = sum;
  __syncthreads();
#pragma unroll
  for (int d = 1; d < 256; d <<= 1) {
    int val = (t >= d) ? s[t - d] : 0;
    __syncthreads();
    s[t] += val;
    __syncthreads();
  }
  int run = s[t] - sum;
  if (base + 0 < n) off[base + 0] = run; run += v0;
  if (base + 1 < n) off[base + 1] = run; run += v1;
  if (base + 2 < n) off[base + 2] = run; run += v2;
  if (base + 3 < n) off[base + 3] = run;
  if (t == 255) bsum[blockIdx.x] = s[255];
}

__global__ void scan_blocks(const int* __restrict__ bsum, int* __restrict__ boff, int nb) {
  __shared__ int s[128];
  int t = threadIdx.x;
  int v = (t < nb) ? bsum[t] : 0;
  s[t] = v;
  __syncthreads();
#pragma unroll
  for (int d = 1; d < 128; d <<= 1) {
    int val = (t >= d) ? s[t - d] : 0;
    __syncthreads();
    s[t] += val;
    __syncthreads();
  }
  if (t < nb) boff[t] = s[t] - v;
}

__global__ void scan_add(int* __restrict__ off, int* __restrict__ cursor,
                         const int* __restrict__ boff, int n, int total) {
  int i = blockIdx.x * blockDim.x + threadIdx.x;
  if (i < n) {
    int o = off[i] + boff[i >> 10];
    off[i] = o;
    cursor[i] = o;
  } else if (i == n) {
    off[n] = total;
  }
}

// scatter edges into CSR slots; src index only (norm factored into aggregate:
// out = dinv[d]*(sum dinv[s]*h[s] + dinv[d]*h[d]) + b).
__global__ void fill_csr(const int* __restrict__ ei, int* __restrict__ cursor,
                         int* __restrict__ csrc) {
  int e = blockIdx.x * blockDim.x + threadIdx.x;
  if (e >= N_EDGES) return;
  int s = ei[e];
  int d = ei[N_EDGES + e];
  int pos = atomicAdd(&cursor[d], 1);
  csrc[pos] = s;
}

// ---------- graph (pooling) ranges ----------

__global__ void gscan(const int* __restrict__ gcnt, int* __restrict__ goff) {
  __shared__ int s[256];
  int t = threadIdx.x;
  int base = t * 4;
  int v0 = (base + 0 < NGRAPH) ? gcnt[base + 0] : 0;
  int v1 = (base + 1 < NGRAPH) ? gcnt[base + 1] : 0;
  int v2 = (base + 2 < NGRAPH) ? gcnt[base + 2] : 0;
  int v3 = (base + 3 < NGRAPH) ? gcnt[base + 3] : 0;
  int sum = v0 + v1 + v2 + v3;
  s[t] = sum;
  __syncthreads();
#pragma unroll
  for (int d = 1; d < 256; d <<= 1) {
    int val = (t >= d) ? s[t - d] : 0;
    __syncthreads();
    s[t] += val;
    __syncthreads();
  }
  int run = s[t] - sum;
  if (base + 0 < NGRAPH) goff[base + 0] = run; run += v0;
  if (base + 1 < NGRAPH) goff[base + 1] = run; run += v1;
  if (base + 2 < NGRAPH) goff[base + 2] = run; run += v2;
  if (base + 3 < NGRAPH) goff[base + 3] = run;
  if (t == 255) goff[NGRAPH] = s[255];
}

// ---------- aggregation ----------
// one 64-lane wave per dst node; lane owns half2 (features 2l,2l+1) = 256 B
// coalesced row per edge. 8 independent gathers in flight. dinv[s] is a
// wave-broadcast load (dinv = 400 KB, L2-resident).
__global__ __launch_bounds__(256)
void aggregate(const __half* __restrict__ h, const int* __restrict__ off,
               const int* __restrict__ csrc, const float* __restrict__ dinv,
               const float* __restrict__ bias, float* __restrict__ out) {
  int gid = blockIdx.x * blockDim.x + threadIdx.x;
  int node = gid >> 6;
  int lane = gid & 63;
  if (node >= N_NODES) return;
  const __half2* h2 = (const __half2*)h;

  int beg = off[node], end = off[node + 1];
  float a0 = 0.f, a1 = 0.f;
  float b0_ = 0.f, b1_ = 0.f;
  float c0 = 0.f, c1 = 0.f;
  float d0 = 0.f, d1 = 0.f;

  int e = beg;
  for (; e + 8 <= end; e += 8) {
    int s0 = csrc[e + 0], s1 = csrc[e + 1], s2 = csrc[e + 2], s3 = csrc[e + 3];
    int s4 = csrc[e + 4], s5 = csrc[e + 5], s6 = csrc[e + 6], s7 = csrc[e + 7];
    float w0 = dinv[s0], w1 = dinv[s1], w2 = dinv[s2], w3 = dinv[s3];
    float w4 = dinv[s4], w5 = dinv[s5], w6 = dinv[s6], w7 = dinv[s7];
    __half2 v0 = h2[(size_t)s0 * 64 + lane];
    __half2 v1 = h2[(size_t)s1 * 64 + lane];
    __half2 v2 = h2[(size_t)s2 * 64 + lane];
    __half2 v3 = h2[(size_t)s3 * 64 + lane];
    __half2 v4 = h2[(size_t)s4 * 64 + lane];
    __half2 v5 = h2[(size_t)s5 * 64 + lane];
    __half2 v6 = h2[(size_t)s6 * 64 + lane];
    __half2 v7 = h2[(size_t)s7 * 64 + lane];
    float2 f0 = __half22float2(v0), f1 = __half22float2(v1);
    float2 f2 = __half22float2(v2), f3 = __half22float2(v3);
    float2 f4 = __half22float2(v4), f5 = __half22float2(v5);
    float2 f6 = __half22float2(v6), f7 = __half22float2(v7);
    a0 = fmaf(w0, f0.x, a0); a1 = fmaf(w0, f0.y, a1);
    b0_ = fmaf(w1, f1.x, b0_); b1_ = fmaf(w1, f1.y, b1_);
    c0 = fmaf(w2, f2.x, c0); c1 = fmaf(w2, f2.y, c1);
    d0 = fmaf(w3, f3.x, d0); d1 = fmaf(w3, f3.y, d1);
    a0 = fmaf(w4, f4.x, a0); a1 = fmaf(w4, f4.y, a1);
    b0_ = fmaf(w5, f5.x, b0_); b1_ = fmaf(w5, f5.y, b1_);
    c0 = fmaf(w6, f6.x, c0); c1 = fmaf(w6, f6.y, c1);
    d0 = fmaf(w7, f7.x, d0); d1 = fmaf(w7, f7.y, d1);
  }
  if (e + 4 <= end) {
    int s0 = csrc[e + 0], s1 = csrc[e + 1], s2 = csrc[e + 2], s3 = csrc[e + 3];
    float w0 = dinv[s0], w1 = dinv[s1], w2 = dinv[s2], w3 = dinv[s3];
    __half2 v0 = h2[(size_t)s0 * 64 + lane];
    __half2 v1 = h2[(size_t)s1 * 64 + lane];
    __half2 v2 = h2[(size_t)s2 * 64 + lane];
    __half2 v3 = h2[(size_t)s3 * 64 + lane];
    float2 f0 = __half22float2(v0), f1 = __half22float2(v1);
    float2 f2 = __half22float2(v2), f3 = __half22float2(v3);
    a0 = fmaf(w0, f0.x, a0); a1 = fmaf(w0, f0.y, a1);
    b0_ = fmaf(w1, f1.x, b0_); b1_ = fmaf(w1, f1.y, b1_);
    c0 = fmaf(w2, f2.x, c0); c1 = fmaf(w2, f2.y, c1);
    d0 = fmaf(w3, f3.x, d0); d1 = fmaf(w3, f3.y, d1);
    e += 4;
  }
  if (e + 2 <= end) {
    int s0 = csrc[e + 0], s1 = csrc[e + 1];
    float w0 = dinv[s0], w1 = dinv[s1];
    __half2 v0 = h2[(size_t)s0 * 64 + lane];
    __half2 v1 = h2[(size_t)s1 * 64 + lane];
    float2 f0 = __half22float2(v0), f1 = __half22float2(v1);
    a0 = fmaf(w0, f0.x, a0); a1 = fmaf(w0, f0.y, a1);
    b0_ = fmaf(w1, f1.x, b0_); b1_ = fmaf(w1, f1.y, b1_);
    e += 2;
  }
  if (e < end) {
    int s0 = csrc[e];
    float w0 = dinv[s0];
    __half2 v0 = h2[(size_t)s0 * 64 + lane];
    float2 f0 = __half22float2(v0);
    a0 = fmaf(w0, f0.x, a0); a1 = fmaf(w0, f0.y, a1);
  }

  float dv = dinv[node];
  float2 vs = __half22float2(h2[(size_t)node * 64 + lane]);
  float s0f = (a0 + b0_) + (c0 + d0) + dv * vs.x;
  float s1f = (a1 + b1_) + (c1 + d1) + dv * vs.y;

  float2 bb = ((const float2*)bias)[lane];
  float2 o;
  o.x = elu1(fmaf(dv, s0f, bb.x));
  o.y = elu1(fmaf(dv, s1f, bb.y));
  ((float2*)out)[(size_t)node * 64 + lane] = o;
}

// ---------- fused max-pool + linear head + softmax ----------
__global__ void pool_head(const float* __restrict__ feat, const int* __restrict__ goff,
                          const float* __restrict__ Wl, const float* __restrict__ bl,
                          float* __restrict__ out) {
  int g = blockIdx.x;
  int t = threadIdx.x;
  int beg = goff[g], end = goff[g + 1];

  float m0 = -INFINITY, m1 = -INFINITY, m2 = -INFINITY, m3 = -INFINITY;
  int i = beg;
  for (; i + 4 <= end; i += 4) {
    m0 = fmaxf(m0, feat[(size_t)(i + 0) * HDIM + t]);
    m1 = fmaxf(m1, feat[(size_t)(i + 1) * HDIM + t]);
    m2 = fmaxf(m2, feat[(size_t)(i + 2) * HDIM + t]);
    m3 = fmaxf(m3, feat[(size_t)(i + 3) * HDIM + t]);
  }
  for (; i < end; ++i) m0 = fmaxf(m0, feat[(size_t)i * HDIM + t]);
  float m = fmaxf(fmaxf(m0, m1), fmaxf(m2, m3));
  if (beg == end) m = 0.f;

  __shared__ float pl[HDIM];
  __shared__ float lg[NCLS];
  pl[t] = m;
  __syncthreads();

  if (t < NCLS) {
    float acc = bl[t];
#pragma unroll
    for (int f = 0; f < HDIM; ++f) acc = fmaf(pl[f], Wl[f * NCLS + t], acc);
    lg[t] = acc;
  }
  __syncthreads();

  if (t < NCLS) {
    float mx = lg[0];
#pragma unroll
    for (int c = 1; c < NCLS; ++c) mx = fmaxf(mx, lg[c]);
    float ssum = 0.f;
#pragma unroll
    for (int c = 0; c < NCLS; ++c) ssum += __expf(lg[c] - mx);
    out[g * NCLS + t] = __expf(lg[t] - mx) / ssum;
  }
}

// ---------- launch ----------

extern "C" void kernel_launch(void* const* d_in, const int* in_sizes, int n_in,
                              void* d_out, int out_size, void* d_ws, size_t ws_size,
                              hipStream_t stream) {
  const float* x    = (const float*)d_in[0];
  const int*   ei   = (const int*)d_in[1];
  const int*   batch= (const int*)d_in[2];
  const float* W0 = (const float*)d_in[3]; const float* b0 = (const float*)d_in[4];
  const float* W1 = (const float*)d_in[5]; const float* b1 = (const float*)d_in[6];
  const float* W2 = (const float*)d_in[7]; const float* b2 = (const float*)d_in[8];
  const float* Wl = (const float*)d_in[9]; const float* bl = (const float*)d_in[10];
  float* out = (float*)d_out;

  char* w = (char*)d_ws;
  auto alloc = [&](size_t bytes) {
    char* p = w;
    w += (bytes + 255) & ~(size_t)255;
    return p;
  };
  int*    cnt    = (int*)   alloc((size_t)NREP * N_NODES * 4);
  int*    off    = (int*)   alloc((size_t)(N_NODES + 1) * 4);
  int*    cursor = (int*)   alloc((size_t)(N_NODES + 1) * 4);
  float*  dinv   = (float*) alloc((size_t)N_NODES * 4);
  int*    bsum   = (int*)   alloc(128 * 4);
  int*    boff   = (int*)   alloc(128 * 4);
  int*    gcnt   = (int*)   alloc((size_t)NGRAPH * 4);
  int*    goff   = (int*)   alloc((size_t)(NGRAPH + 1) * 4);
  int*    csrc   = (int*)   alloc((size_t)N_EDGES * 4);
  __half* hbuf   = (__half*)alloc((size_t)N_NODES * HDIM * 2);
  float*  feat   = (float*) alloc((size_t)N_NODES * HDIM * 4);

  hipMemsetAsync(cnt, 0, (size_t)NREP * N_NODES * 4, stream);
  hipMemsetAsync(gcnt, 0, (size_t)NGRAPH * 4, stream);

  // GEMM layer 0 overlapped with degree/graph histograms (independent work)
  hist_gemm0<<<GEMM_BLOCKS + HIST_BLOCKS, 256, 0, stream>>>(
      x, W0, hbuf, ei, batch, cnt, gcnt);

  int nb = (N_NODES + 1023) / 1024;
  scan_local<<<nb, 256, 0, stream>>>(cnt, off, bsum, dinv, N_NODES);
  scan_blocks<<<1, 128, 0, stream>>>(bsum, boff, nb);
  scan_add<<<(N_NODES + 1 + 255) / 256, 256, 0, stream>>>(off, cursor, boff, N_NODES, N_EDGES);
  fill_csr<<<(N_EDGES + 255) / 256, 256, 0, stream>>>(ei, cursor, csrc);

  gscan<<<1, 256, 0, stream>>>(gcnt, goff);

  const float* bs[3] = {b0, b1, b2};
  // layer 0 GEMM already done inside hist_gemm0
  aggregate<<<((size_t)N_NODES * 64 + 255) / 256, 256, 0, stream>>>(
      hbuf, off, csrc, dinv, bs[0], feat);
  for (int l = 1; l < 3; ++l) {
    const float* Wcur = (l == 1) ? W1 : W2;
    gemm_xw<<<GEMM_BLOCKS, 256, 0, stream>>>(feat, Wcur, hbuf, N_NODES);
    aggregate<<<((size_t)N_NODES * 64 + 255) / 256, 256, 0, stream>>>(
        hbuf, off, csrc, dinv, bs[l], feat);
  }

  pool_head<<<NGRAPH, 128, 0, stream>>>(feat, goff, Wl, bl, out);
}

// Round 6
// 630.759 us; speedup vs baseline: 1.1439x; 1.1439x over previous
//
#include <hip/hip_runtime.h>
#include <hip/hip_fp16.h>
#include <math.h>

#define N_NODES 100000
#define N_EDGES 1600000
#define HDIM    128
#define NCLS    10
#define NGRAPH  1000
#define GEMM_BLOCKS  ((N_NODES + 127) / 128)   // 782
#define GEMM_THREADS (GEMM_BLOCKS * 256)       // 200192; ceil(E/threads)=8 edges/thread

static __device__ __forceinline__ float elu1(float x) {
  return x > 0.f ? x : (__expf(x) - 1.f);
}

// ---------- GEMM body: Ch[n,128](fp16) = A[n,128] @ W[128,128](f32) ----------
// 128x128 tile/block, W whole in LDS (64 KB), 8x8 reg tile/thread, pipelined
// A loads. A is f32 (layer 0, from input x) or fp16 (layers 1-2, from feat).
template <bool AHALF>
__device__ __forceinline__
void gemm_body(const void* __restrict__ Av, const float* __restrict__ W,
               __half* __restrict__ Ch, int nrows, float* Wl, int bid) {
  int tid = threadIdx.x;
  {
    const float4* W4 = (const float4*)W;
    float4* Wl4 = (float4*)Wl;
    for (int i = tid; i < 128 * 128 / 4; i += 256) Wl4[i] = W4[i];
  }
  __syncthreads();

  int ty = tid >> 4;
  int tx = tid & 15;
  int row0 = bid * 128 + ty * 8;

  size_t rbase[8];
#pragma unroll
  for (int r = 0; r < 8; ++r) {
    int rr = row0 + r;
    if (rr > nrows - 1) rr = nrows - 1;  // clamp tail (stores are guarded)
    rbase[r] = (size_t)rr * HDIM;
  }

  float4 acc0[8], acc1[8];
#pragma unroll
  for (int r = 0; r < 8; ++r) {
    acc0[r] = make_float4(0.f, 0.f, 0.f, 0.f);
    acc1[r] = make_float4(0.f, 0.f, 0.f, 0.f);
  }

#define FMA8(xs, w0, w1, r)                     \
  acc0[r].x = fmaf(xs, w0.x, acc0[r].x);        \
  acc0[r].y = fmaf(xs, w0.y, acc0[r].y);        \
  acc0[r].z = fmaf(xs, w0.z, acc0[r].z);        \
  acc0[r].w = fmaf(xs, w0.w, acc0[r].w);        \
  acc1[r].x = fmaf(xs, w1.x, acc1[r].x);        \
  acc1[r].y = fmaf(xs, w1.y, acc1[r].y);        \
  acc1[r].z = fmaf(xs, w1.z, acc1[r].z);        \
  acc1[r].w = fmaf(xs, w1.w, acc1[r].w);

  if constexpr (AHALF) {
    const __half* Ah = (const __half*)Av;
    uint4 cur[8], nxt[8];
#pragma unroll
    for (int r = 0; r < 8; ++r) cur[r] = *(const uint4*)(Ah + rbase[r]);
    for (int k = 0; k < 128; k += 8) {
      if (k + 8 < 128) {
#pragma unroll
        for (int r = 0; r < 8; ++r) nxt[r] = *(const uint4*)(Ah + rbase[r] + k + 8);
      }
#pragma unroll
      for (int kk = 0; kk < 8; ++kk) {
        const float* wrow = &Wl[(k + kk) * 128];
        float4 w0 = *(const float4*)(wrow + tx * 4);
        float4 w1 = *(const float4*)(wrow + 64 + tx * 4);
#pragma unroll
        for (int r = 0; r < 8; ++r) {
          __half2 hp = ((const __half2*)&cur[r])[kk >> 1];
          float xs = (kk & 1) ? __high2float(hp) : __low2float(hp);
          FMA8(xs, w0, w1, r)
        }
      }
#pragma unroll
      for (int r = 0; r < 8; ++r) cur[r] = nxt[r];
    }
  } else {
    const float* Af = (const float*)Av;
    float4 xa[8], xb[8];
#pragma unroll
    for (int r = 0; r < 8; ++r) xa[r] = *(const float4*)(Af + rbase[r]);
    for (int k = 0; k < 128; k += 8) {
#pragma unroll
      for (int r = 0; r < 8; ++r) xb[r] = *(const float4*)(Af + rbase[r] + k + 4);
#pragma unroll
      for (int kk = 0; kk < 4; ++kk) {
        const float* wrow = &Wl[(k + kk) * 128];
        float4 w0 = *(const float4*)(wrow + tx * 4);
        float4 w1 = *(const float4*)(wrow + 64 + tx * 4);
#pragma unroll
        for (int r = 0; r < 8; ++r) {
          float xs = ((const float*)&xa[r])[kk];
          FMA8(xs, w0, w1, r)
        }
      }
      if (k + 8 < 128) {
#pragma unroll
        for (int r = 0; r < 8; ++r) xa[r] = *(const float4*)(Af + rbase[r] + k + 8);
      }
#pragma unroll
      for (int kk = 0; kk < 4; ++kk) {
        const float* wrow = &Wl[(k + 4 + kk) * 128];
        float4 w0 = *(const float4*)(wrow + tx * 4);
        float4 w1 = *(const float4*)(wrow + 64 + tx * 4);
#pragma unroll
        for (int r = 0; r < 8; ++r) {
          float xs = ((const float*)&xb[r])[kk];
          FMA8(xs, w0, w1, r)
        }
      }
    }
  }
#undef FMA8

#pragma unroll
  for (int r = 0; r < 8; ++r) {
    int rrow = row0 + r;
    if (rrow < nrows) {
      __half2 l0 = __floats2half2_rn(acc0[r].x, acc0[r].y);
      __half2 l1 = __floats2half2_rn(acc0[r].z, acc0[r].w);
      __half2 h0 = __floats2half2_rn(acc1[r].x, acc1[r].y);
      __half2 h1 = __floats2half2_rn(acc1[r].z, acc1[r].w);
      uint2 p0, p1;
      p0.x = *(unsigned*)&l0; p0.y = *(unsigned*)&l1;
      p1.x = *(unsigned*)&h0; p1.y = *(unsigned*)&h1;
      *(uint2*)&Ch[(size_t)rrow * HDIM + tx * 4] = p0;
      *(uint2*)&Ch[(size_t)rrow * HDIM + 64 + tx * 4] = p1;
    }
  }
}

// ---------- layer-0 GEMM with embedded histograms ----------
// Per-thread overlap (R5 post-mortem: separate-block fusion starved the
// histogram's occupancy). Each thread fires 8 edge atomics BEFORE the K-loop
// (fire-and-forget on the VMEM pipe, drains behind ~7 us of FMA work) and
// stores the returned within-dst ranks AFTER the C-store. Ranks make
// fill_csr atomic-free.
__global__ __launch_bounds__(256, 2)
void gemm0_hist(const float* __restrict__ A, const float* __restrict__ W,
                __half* __restrict__ Ch,
                const int* __restrict__ ei, const int* __restrict__ batch,
                int* __restrict__ cnt, int* __restrict__ gcnt,
                int* __restrict__ erank) {
  int gtid = blockIdx.x * 256 + threadIdx.x;
  int ranks[8];
#pragma unroll
  for (int k = 0; k < 8; ++k) {
    int e = gtid + k * GEMM_THREADS;
    if (e < N_EDGES) ranks[k] = atomicAdd(&cnt[ei[N_EDGES + e]], 1);
  }
  if (gtid < N_NODES) atomicAdd(&gcnt[batch[gtid]], 1);

  __shared__ float Wl[128 * 128];
  gemm_body<false>(A, W, Ch, N_NODES, Wl, blockIdx.x);

  // rank stores last: the s_waitcnt on the atomic returns lands after compute
#pragma unroll
  for (int k = 0; k < 8; ++k) {
    int e = gtid + k * GEMM_THREADS;
    if (e < N_EDGES) erank[e] = ranks[k];
  }
}

__global__ __launch_bounds__(256, 2)
void gemm_h(const __half* __restrict__ A, const float* __restrict__ W,
            __half* __restrict__ Ch, int nrows) {
  __shared__ float Wl[128 * 128];
  gemm_body<true>(A, W, Ch, nrows, Wl, blockIdx.x);
}

// ---------- CSR build ----------

// block-local exclusive scan: 1024 elements/block (256 thr x 4); emits
// dinv[i] = rsqrt(deg_in + 1) while cnt is in registers.
__global__ void scan_local(const int* __restrict__ cnt, int* __restrict__ off,
                           int* __restrict__ bsum, float* __restrict__ dinv, int n) {
  __shared__ int s[256];
  int t = threadIdx.x;
  int base = blockIdx.x * 1024 + t * 4;
  int v0 = (base + 0 < n) ? cnt[base + 0] : 0;
  int v1 = (base + 1 < n) ? cnt[base + 1] : 0;
  int v2 = (base + 2 < n) ? cnt[base + 2] : 0;
  int v3 = (base + 3 < n) ? cnt[base + 3] : 0;
  if (base + 0 < n) dinv[base + 0] = rsqrtf((float)(v0 + 1));
  if (base + 1 < n) dinv[base + 1] = rsqrtf((float)(v1 + 1));
  if (base + 2 < n) dinv[base + 2] = rsqrtf((float)(v2 + 1));
  if (base + 3 < n) dinv[base + 3] = rsqrtf((float)(v3 + 1));
  int sum = v0 + v1 + v2 + v3;
  s[t] = sum;
  __syncthreads();
#pragma unroll
  for (int d = 1; d < 256; d <<= 1) {
    int val = (t >= d) ? s[t - d] : 0;
    __syncthreads();
    s[t] += val;
    __syncthreads();
  }
  int run = s[t] - sum;
  if (base + 0 < n) off[base + 0] = run; run += v0;
  if (base + 1 < n) off[base + 1] = run; run += v1;
  if (base + 2 < n) off[base + 2] = run; run += v2;
  if (base + 3 < n) off[base + 3] = run;
  if (t == 255) bsum[blockIdx.x] = s[255];
}

__global__ void scan_blocks(const int* __restrict__ bsum, int* __restrict__ boff, int nb) {
  __shared__ int s[128];
  int t = threadIdx.x;
  int v = (t < nb) ? bsum[t] : 0;
  s[t] = v;
  __syncthreads();
#pragma unroll
  for (int d = 1; d < 128; d <<= 1) {
    int val = (t >= d) ? s[t - d] : 0;
    __syncthreads();
    s[t] += val;
    __syncthreads();
  }
  if (t < nb) boff[t] = s[t] - v;
}

__global__ void scan_add(int* __restrict__ off, const int* __restrict__ boff,
                         int n, int total) {
  int i = blockIdx.x * blockDim.x + threadIdx.x;
  if (i < n) {
    off[i] += boff[i >> 10];
  } else if (i == n) {
    off[n] = total;
  }
}

// atomic-free scatter (ranks precomputed in gemm0_hist)
__global__ void fill_csr(const int* __restrict__ ei, const int* __restrict__ off,
                         const int* __restrict__ erank, int* __restrict__ csrc) {
  int e = blockIdx.x * blockDim.x + threadIdx.x;
  if (e >= N_EDGES) return;
  csrc[off[ei[N_EDGES + e]] + erank[e]] = ei[e];
}

// ---------- graph (pooling) ranges ----------

__global__ void gscan(const int* __restrict__ gcnt, int* __restrict__ goff) {
  __shared__ int s[256];
  int t = threadIdx.x;
  int base = t * 4;
  int v0 = (base + 0 < NGRAPH) ? gcnt[base + 0] : 0;
  int v1 = (base + 1 < NGRAPH) ? gcnt[base + 1] : 0;
  int v2 = (base + 2 < NGRAPH) ? gcnt[base + 2] : 0;
  int v3 = (base + 3 < NGRAPH) ? gcnt[base + 3] : 0;
  int sum = v0 + v1 + v2 + v3;
  s[t] = sum;
  __syncthreads();
#pragma unroll
  for (int d = 1; d < 256; d <<= 1) {
    int val = (t >= d) ? s[t - d] : 0;
    __syncthreads();
    s[t] += val;
    __syncthreads();
  }
  int run = s[t] - sum;
  if (base + 0 < NGRAPH) goff[base + 0] = run; run += v0;
  if (base + 1 < NGRAPH) goff[base + 1] = run; run += v1;
  if (base + 2 < NGRAPH) goff[base + 2] = run; run += v2;
  if (base + 3 < NGRAPH) goff[base + 3] = run;
  if (t == 255) goff[NGRAPH] = s[255];
}

// ---------- aggregation ----------
// one 64-lane wave per dst node; lane owns half2 (features 2l,2l+1) = 256 B
// coalesced row per edge; 8 independent gathers in flight; dinv[s] is a
// wave-broadcast load; fp16 output (feat also fp16 now).
__global__ __launch_bounds__(256)
void aggregate(const __half* __restrict__ h, const int* __restrict__ off,
               const int* __restrict__ csrc, const float* __restrict__ dinv,
               const float* __restrict__ bias, __half* __restrict__ out) {
  int gid = blockIdx.x * blockDim.x + threadIdx.x;
  int node = gid >> 6;
  int lane = gid & 63;
  if (node >= N_NODES) return;
  const __half2* h2 = (const __half2*)h;

  int beg = off[node], end = off[node + 1];
  float a0 = 0.f, a1 = 0.f;
  float b0_ = 0.f, b1_ = 0.f;
  float c0 = 0.f, c1 = 0.f;
  float d0 = 0.f, d1 = 0.f;

  int e = beg;
  for (; e + 8 <= end; e += 8) {
    int s0 = csrc[e + 0], s1 = csrc[e + 1], s2 = csrc[e + 2], s3 = csrc[e + 3];
    int s4 = csrc[e + 4], s5 = csrc[e + 5], s6 = csrc[e + 6], s7 = csrc[e + 7];
    float w0 = dinv[s0], w1 = dinv[s1], w2 = dinv[s2], w3 = dinv[s3];
    float w4 = dinv[s4], w5 = dinv[s5], w6 = dinv[s6], w7 = dinv[s7];
    __half2 v0 = h2[(size_t)s0 * 64 + lane];
    __half2 v1 = h2[(size_t)s1 * 64 + lane];
    __half2 v2 = h2[(size_t)s2 * 64 + lane];
    __half2 v3 = h2[(size_t)s3 * 64 + lane];
    __half2 v4 = h2[(size_t)s4 * 64 + lane];
    __half2 v5 = h2[(size_t)s5 * 64 + lane];
    __half2 v6 = h2[(size_t)s6 * 64 + lane];
    __half2 v7 = h2[(size_t)s7 * 64 + lane];
    float2 f0 = __half22float2(v0), f1 = __half22float2(v1);
    float2 f2 = __half22float2(v2), f3 = __half22float2(v3);
    float2 f4 = __half22float2(v4), f5 = __half22float2(v5);
    float2 f6 = __half22float2(v6), f7 = __half22float2(v7);
    a0 = fmaf(w0, f0.x, a0); a1 = fmaf(w0, f0.y, a1);
    b0_ = fmaf(w1, f1.x, b0_); b1_ = fmaf(w1, f1.y, b1_);
    c0 = fmaf(w2, f2.x, c0); c1 = fmaf(w2, f2.y, c1);
    d0 = fmaf(w3, f3.x, d0); d1 = fmaf(w3, f3.y, d1);
    a0 = fmaf(w4, f4.x, a0); a1 = fmaf(w4, f4.y, a1);
    b0_ = fmaf(w5, f5.x, b0_); b1_ = fmaf(w5, f5.y, b1_);
    c0 = fmaf(w6, f6.x, c0); c1 = fmaf(w6, f6.y, c1);
    d0 = fmaf(w7, f7.x, d0); d1 = fmaf(w7, f7.y, d1);
  }
  if (e + 4 <= end) {
    int s0 = csrc[e + 0], s1 = csrc[e + 1], s2 = csrc[e + 2], s3 = csrc[e + 3];
    float w0 = dinv[s0], w1 = dinv[s1], w2 = dinv[s2], w3 = dinv[s3];
    __half2 v0 = h2[(size_t)s0 * 64 + lane];
    __half2 v1 = h2[(size_t)s1 * 64 + lane];
    __half2 v2 = h2[(size_t)s2 * 64 + lane];
    __half2 v3 = h2[(size_t)s3 * 64 + lane];
    float2 f0 = __half22float2(v0), f1 = __half22float2(v1);
    float2 f2 = __half22float2(v2), f3 = __half22float2(v3);
    a0 = fmaf(w0, f0.x, a0); a1 = fmaf(w0, f0.y, a1);
    b0_ = fmaf(w1, f1.x, b0_); b1_ = fmaf(w1, f1.y, b1_);
    c0 = fmaf(w2, f2.x, c0); c1 = fmaf(w2, f2.y, c1);
    d0 = fmaf(w3, f3.x, d0); d1 = fmaf(w3, f3.y, d1);
    e += 4;
  }
  if (e + 2 <= end) {
    int s0 = csrc[e + 0], s1 = csrc[e + 1];
    float w0 = dinv[s0], w1 = dinv[s1];
    __half2 v0 = h2[(size_t)s0 * 64 + lane];
    __half2 v1 = h2[(size_t)s1 * 64 + lane];
    float2 f0 = __half22float2(v0), f1 = __half22float2(v1);
    a0 = fmaf(w0, f0.x, a0); a1 = fmaf(w0, f0.y, a1);
    b0_ = fmaf(w1, f1.x, b0_); b1_ = fmaf(w1, f1.y, b1_);
    e += 2;
  }
  if (e < end) {
    int s0 = csrc[e];
    float w0 = dinv[s0];
    __half2 v0 = h2[(size_t)s0 * 64 + lane];
    float2 f0 = __half22float2(v0);
    a0 = fmaf(w0, f0.x, a0); a1 = fmaf(w0, f0.y, a1);
  }

  float dv = dinv[node];
  float2 vs = __half22float2(h2[(size_t)node * 64 + lane]);
  float s0f = (a0 + b0_) + (c0 + d0) + dv * vs.x;
  float s1f = (a1 + b1_) + (c1 + d1) + dv * vs.y;

  float2 bb = ((const float2*)bias)[lane];
  float ox = elu1(fmaf(dv, s0f, bb.x));
  float oy = elu1(fmaf(dv, s1f, bb.y));
  ((__half2*)out)[(size_t)node * 64 + lane] = __floats2half2_rn(ox, oy);
}

// ---------- fused max-pool + linear head + softmax ----------
__global__ void pool_head(const __half* __restrict__ feat, const int* __restrict__ goff,
                          const float* __restrict__ Wl, const float* __restrict__ bl,
                          float* __restrict__ out) {
  int g = blockIdx.x;
  int t = threadIdx.x;
  int beg = goff[g], end = goff[g + 1];

  float m0 = -INFINITY, m1 = -INFINITY, m2 = -INFINITY, m3 = -INFINITY;
  int i = beg;
  for (; i + 4 <= end; i += 4) {
    m0 = fmaxf(m0, __half2float(feat[(size_t)(i + 0) * HDIM + t]));
    m1 = fmaxf(m1, __half2float(feat[(size_t)(i + 1) * HDIM + t]));
    m2 = fmaxf(m2, __half2float(feat[(size_t)(i + 2) * HDIM + t]));
    m3 = fmaxf(m3, __half2float(feat[(size_t)(i + 3) * HDIM + t]));
  }
  for (; i < end; ++i) m0 = fmaxf(m0, __half2float(feat[(size_t)i * HDIM + t]));
  float m = fmaxf(fmaxf(m0, m1), fmaxf(m2, m3));
  if (beg == end) m = 0.f;

  __shared__ float pl[HDIM];
  __shared__ float lg[NCLS];
  pl[t] = m;
  __syncthreads();

  if (t < NCLS) {
    float acc = bl[t];
#pragma unroll
    for (int f = 0; f < HDIM; ++f) acc = fmaf(pl[f], Wl[f * NCLS + t], acc);
    lg[t] = acc;
  }
  __syncthreads();

  if (t < NCLS) {
    float mx = lg[0];
#pragma unroll
    for (int c = 1; c < NCLS; ++c) mx = fmaxf(mx, lg[c]);
    float ssum = 0.f;
#pragma unroll
    for (int c = 0; c < NCLS; ++c) ssum += __expf(lg[c] - mx);
    out[g * NCLS + t] = __expf(lg[t] - mx) / ssum;
  }
}

// ---------- launch ----------

extern "C" void kernel_launch(void* const* d_in, const int* in_sizes, int n_in,
                              void* d_out, int out_size, void* d_ws, size_t ws_size,
                              hipStream_t stream) {
  const float* x    = (const float*)d_in[0];
  const int*   ei   = (const int*)d_in[1];
  const int*   batch= (const int*)d_in[2];
  const float* W0 = (const float*)d_in[3]; const float* b0 = (const float*)d_in[4];
  const float* W1 = (const float*)d_in[5]; const float* b1 = (const float*)d_in[6];
  const float* W2 = (const float*)d_in[7]; const float* b2 = (const float*)d_in[8];
  const float* Wl = (const float*)d_in[9]; const float* bl = (const float*)d_in[10];
  float* out = (float*)d_out;

  char* w = (char*)d_ws;
  auto alloc = [&](size_t bytes) {
    char* p = w;
    w += (bytes + 255) & ~(size_t)255;
    return p;
  };
  int*    cnt    = (int*)   alloc((size_t)N_NODES * 4);
  int*    off    = (int*)   alloc((size_t)(N_NODES + 1) * 4);
  float*  dinv   = (float*) alloc((size_t)N_NODES * 4);
  int*    bsum   = (int*)   alloc(128 * 4);
  int*    boff   = (int*)   alloc(128 * 4);
  int*    gcnt   = (int*)   alloc((size_t)NGRAPH * 4);
  int*    goff   = (int*)   alloc((size_t)(NGRAPH + 1) * 4);
  int*    erank  = (int*)   alloc((size_t)N_EDGES * 4);
  int*    csrc   = (int*)   alloc((size_t)N_EDGES * 4);
  __half* hbuf   = (__half*)alloc((size_t)N_NODES * HDIM * 2);
  __half* feat   = (__half*)alloc((size_t)N_NODES * HDIM * 2);

  hipMemsetAsync(cnt, 0, (size_t)N_NODES * 4, stream);
  hipMemsetAsync(gcnt, 0, (size_t)NGRAPH * 4, stream);

  // layer-0 GEMM with embedded degree/graph histograms (per-thread overlap)
  gemm0_hist<<<GEMM_BLOCKS, 256, 0, stream>>>(x, W0, hbuf, ei, batch, cnt, gcnt, erank);

  int nb = (N_NODES + 1023) / 1024;
  scan_local<<<nb, 256, 0, stream>>>(cnt, off, bsum, dinv, N_NODES);
  scan_blocks<<<1, 128, 0, stream>>>(bsum, boff, nb);
  scan_add<<<(N_NODES + 1 + 255) / 256, 256, 0, stream>>>(off, boff, N_NODES, N_EDGES);
  fill_csr<<<(N_EDGES + 255) / 256, 256, 0, stream>>>(ei, off, erank, csrc);

  gscan<<<1, 256, 0, stream>>>(gcnt, goff);

  const float* bs[3] = {b0, b1, b2};
  aggregate<<<((size_t)N_NODES * 64 + 255) / 256, 256, 0, stream>>>(
      hbuf, off, csrc, dinv, bs[0], feat);
  for (int l = 1; l < 3; ++l) {
    const float* Wcur = (l == 1) ? W1 : W2;
    gemm_h<<<GEMM_BLOCKS, 256, 0, stream>>>(feat, Wcur, hbuf, N_NODES);
    aggregate<<<((size_t)N_NODES * 64 + 255) / 256, 256, 0, stream>>>(
        hbuf, off, csrc, dinv, bs[l], feat);
  }

  pool_head<<<NGRAPH, 128, 0, stream>>>(feat, goff, Wl, bl, out);
}